// Round 1
// baseline (73.636 us; speedup 1.0000x reference)
//
#include <hip/hip_runtime.h>
#include <math.h>

#define PI_F 3.14159265358979323846f

__device__ __forceinline__ float fast_tanh(float v) {
    float a = fabsf(v);
    float e = __expf(2.0f * a);                       // exp(2|v|)
    float r = 1.0f - 2.0f * __builtin_amdgcn_rcpf(e + 1.0f);
    return copysignf(r, v);
}

__global__ __launch_bounds__(256) void qdqn_kernel(
    const float* __restrict__ x,      // (B,4)
    const float* __restrict__ w_emb,  // (4,)
    const float* __restrict__ qp,     // (32,)
    const float* __restrict__ Wmat,   // (4,4) row-major [action][wire]
    const float* __restrict__ bias,   // (4,)
    float* __restrict__ out,          // (B,4)
    int nbatch) {
    int b = blockIdx.x * 256 + threadIdx.x;
    if (b >= nbatch) return;

    const float4 xv = reinterpret_cast<const float4*>(x)[b];

    // RX half-angles: xe/2 = (pi/2) * tanh(w_emb * x); identical in all 4 layers.
    float cx[4], sx[4];
    {
        const float xs0 = xv.x, xs1 = xv.y, xs2 = xv.z, xs3 = xv.w;
        float a0 = 0.5f * PI_F * fast_tanh(w_emb[0] * xs0);
        float a1 = 0.5f * PI_F * fast_tanh(w_emb[1] * xs1);
        float a2 = 0.5f * PI_F * fast_tanh(w_emb[2] * xs2);
        float a3 = 0.5f * PI_F * fast_tanh(w_emb[3] * xs3);
        __sincosf(a0, &sx[0], &cx[0]);
        __sincosf(a1, &sx[1], &cx[1]);
        __sincosf(a2, &sx[2], &cx[2]);
        __sincosf(a3, &sx[3], &cx[3]);
    }

    // State: wire w <-> bit position (3-w); idx = w0*8 + w1*4 + w2*2 + w3.
    float re[16], im[16];
    #pragma unroll
    for (int i = 0; i < 16; ++i) { re[i] = 0.0f; im[i] = 0.0f; }
    re[0] = 1.0f;

// RX(t): [[c, -is],[-is, c]]
#define RX_GATE(W) { \
    const int pb = 3 - (W); const float c = cx[(W)], s = sx[(W)]; \
    _Pragma("unroll") \
    for (int i = 0; i < 16; ++i) { \
        if (((i >> pb) & 1) == 0) { \
            const int j = i | (1 << pb); \
            const float r0 = re[i], m0 = im[i], r1 = re[j], m1 = im[j]; \
            re[i] = fmaf(c, r0,  s * m1); \
            im[i] = fmaf(c, m0, -s * r1); \
            re[j] = fmaf(c, r1,  s * m0); \
            im[j] = fmaf(c, m1, -s * r0); \
        } } }

// RY(t): [[c, -s],[s, c]]
#define RY_GATE(W, C, S) { \
    const int pb = 3 - (W); const float c = (C), s = (S); \
    _Pragma("unroll") \
    for (int i = 0; i < 16; ++i) { \
        if (((i >> pb) & 1) == 0) { \
            const int j = i | (1 << pb); \
            const float r0 = re[i], m0 = im[i], r1 = re[j], m1 = im[j]; \
            re[i] = fmaf(c, r0, -s * r1); \
            im[i] = fmaf(c, m0, -s * m1); \
            re[j] = fmaf(s, r0,  c * r1); \
            im[j] = fmaf(s, m0,  c * m1); \
        } } }

// RZ(t): diag(c - is, c + is)
#define RZ_GATE(W, C, S) { \
    const int pb = 3 - (W); const float c = (C), s = (S); \
    _Pragma("unroll") \
    for (int i = 0; i < 16; ++i) { \
        const float r = re[i], m = im[i]; \
        if ((i >> pb) & 1) { re[i] = fmaf(c, r, -s * m); im[i] = fmaf(c, m,  s * r); } \
        else               { re[i] = fmaf(c, r,  s * m); im[i] = fmaf(c, m, -s * r); } \
    } }

// CNOT(control C, target T): swap target bit where control bit set (register rename)
#define CNOT_GATE(C, T) { \
    const int pc = 3 - (C), pt = 3 - (T); \
    _Pragma("unroll") \
    for (int i = 0; i < 16; ++i) { \
        if (((i >> pc) & 1) && !((i >> pt) & 1)) { \
            const int j = i | (1 << pt); \
            const float tr = re[i]; re[i] = re[j]; re[j] = tr; \
            const float tm = im[i]; im[i] = im[j]; im[j] = tm; \
        } } }

    #pragma unroll
    for (int l = 0; l < 4; ++l) {
        RX_GATE(0) RX_GATE(1) RX_GATE(2) RX_GATE(3)

        // batch-uniform angles: half-angle sincos of q_params[8l .. 8l+8)
        const int o = 8 * l;
        float cq[8], sq[8];
        #pragma unroll
        for (int k = 0; k < 8; ++k) {
            __sincosf(0.5f * qp[o + k], &sq[k], &cq[k]);
        }

        RY_GATE(0, cq[0], sq[0])
        RY_GATE(1, cq[1], sq[1])
        RY_GATE(2, cq[2], sq[2])
        RY_GATE(3, cq[3], sq[3])

        RZ_GATE(0, cq[4], sq[4])
        RZ_GATE(1, cq[5], sq[5])
        RZ_GATE(2, cq[6], sq[6])
        RZ_GATE(3, cq[7], sq[7])

        CNOT_GATE(2, 3) CNOT_GATE(1, 2) CNOT_GATE(0, 1) CNOT_GATE(3, 0)
    }

    // probabilities and Z expectations
    float p[16];
    #pragma unroll
    for (int i = 0; i < 16; ++i) p[i] = fmaf(re[i], re[i], im[i] * im[i]);

    float ev[4];
    #pragma unroll
    for (int w = 0; w < 4; ++w) {
        const int pb = 3 - w;
        float acc = 0.0f;
        #pragma unroll
        for (int i = 0; i < 16; ++i)
            acc += ((i >> pb) & 1) ? -p[i] : p[i];
        ev[w] = fmaxf(acc, 0.0f);   // relu
    }

    float4 o4;
    o4.x = fmaf(ev[0], Wmat[0],  fmaf(ev[1], Wmat[1],  fmaf(ev[2], Wmat[2],  fmaf(ev[3], Wmat[3],  bias[0]))));
    o4.y = fmaf(ev[0], Wmat[4],  fmaf(ev[1], Wmat[5],  fmaf(ev[2], Wmat[6],  fmaf(ev[3], Wmat[7],  bias[1]))));
    o4.z = fmaf(ev[0], Wmat[8],  fmaf(ev[1], Wmat[9],  fmaf(ev[2], Wmat[10], fmaf(ev[3], Wmat[11], bias[2]))));
    o4.w = fmaf(ev[0], Wmat[12], fmaf(ev[1], Wmat[13], fmaf(ev[2], Wmat[14], fmaf(ev[3], Wmat[15], bias[3]))));
    reinterpret_cast<float4*>(out)[b] = o4;
}

extern "C" void kernel_launch(void* const* d_in, const int* in_sizes, int n_in,
                              void* d_out, int out_size, void* d_ws, size_t ws_size,
                              hipStream_t stream) {
    const float* x     = (const float*)d_in[0];
    const float* w_emb = (const float*)d_in[1];
    const float* qp    = (const float*)d_in[2];
    const float* Wmat  = (const float*)d_in[3];
    const float* bias  = (const float*)d_in[4];
    float* out = (float*)d_out;

    const int nbatch = in_sizes[0] / 4;
    const int block = 256;
    const int grid = (nbatch + block - 1) / block;
    hipLaunchKernelGGL(qdqn_kernel, dim3(grid), dim3(block), 0, stream,
                       x, w_emb, qp, Wmat, bias, out, nbatch);
}

// Round 4
// 69.400 us; speedup vs baseline: 1.0610x; 1.0610x over previous
//
#include <hip/hip_runtime.h>
#include <math.h>

#define PI_F 3.14159265358979323846f

__device__ __forceinline__ float fast_tanh(float v) {
    float a = fabsf(v);
    float e = __expf(2.0f * a);                       // exp(2|v|)
    float r = 1.0f - 2.0f * __builtin_amdgcn_rcpf(e + 1.0f);
    return copysignf(r, v);
}

// Apply SU(2) gate U = [[A, -conj(B)],[B, conj(A)]] on wire W (bit 3-W).
// out0 = A a0 - conj(B) a1 ; out1 = B a0 + conj(A) a1
#define SU2_GATE(W, AR, AI, BR, BI) { \
    const float Ar_ = (AR), Ai_ = (AI), Br_ = (BR), Bi_ = (BI); \
    _Pragma("unroll") \
    for (int i_ = 0; i_ < 16; ++i_) { \
        if (((i_ >> (3 - (W))) & 1) == 0) { \
            const int j_ = i_ | (1 << (3 - (W))); \
            const float a0r = re[i_], a0i = im[i_], a1r = re[j_], a1i = im[j_]; \
            re[i_] = fmaf(Ar_, a0r, fmaf(-Ai_, a0i, fmaf(-Br_, a1r, -Bi_ * a1i))); \
            im[i_] = fmaf(Ar_, a0i, fmaf( Ai_, a0r, fmaf(-Br_, a1i,  Bi_ * a1r))); \
            re[j_] = fmaf(Br_, a0r, fmaf(-Bi_, a0i, fmaf( Ar_, a1r,  Ai_ * a1i))); \
            im[j_] = fmaf(Br_, a0i, fmaf( Bi_, a0r, fmaf( Ar_, a1i, -Ai_ * a1r))); \
        } } }

// CNOT(control C, target T): pure register permutation
#define CNOT_GATE(C, T) { \
    const int pc_ = 3 - (C), pt_ = 3 - (T); \
    _Pragma("unroll") \
    for (int i_ = 0; i_ < 16; ++i_) { \
        if (((i_ >> pc_) & 1) && !((i_ >> pt_) & 1)) { \
            const int j_ = i_ | (1 << pt_); \
            const float tr_ = re[i_]; re[i_] = re[j_]; re[j_] = tr_; \
            const float tm_ = im[i_]; im[i_] = im[j_]; im[j_] = tm_; \
        } } }

__global__ __launch_bounds__(256) void qdqn_kernel(
    const float* __restrict__ x,      // (B,4)
    const float* __restrict__ w_emb,  // (4,)
    const float* __restrict__ qp,     // (32,)
    const float* __restrict__ Wmat,   // (4,4) [action][wire]
    const float* __restrict__ bias,   // (4,)
    float* __restrict__ out,          // (B,4)
    int nbatch) {
    int b = blockIdx.x * 256 + threadIdx.x;
    if (b >= nbatch) return;

    const float4 xv = reinterpret_cast<const float4*>(x)[b];

    // RX half-angles (identical across layers): (pi/2)*tanh(w_emb*x)
    float cx[4], sx[4];
    {
        float a0 = 0.5f * PI_F * fast_tanh(w_emb[0] * xv.x);
        float a1 = 0.5f * PI_F * fast_tanh(w_emb[1] * xv.y);
        float a2 = 0.5f * PI_F * fast_tanh(w_emb[2] * xv.z);
        float a3 = 0.5f * PI_F * fast_tanh(w_emb[3] * xv.w);
        __sincosf(a0, &sx[0], &cx[0]);
        __sincosf(a1, &sx[1], &cx[1]);
        __sincosf(a2, &sx[2], &cx[2]);
        __sincosf(a3, &sx[3], &cx[3]);
    }

    // State: wire w <-> bit (3-w); idx = a0*8 + a1*4 + a2*2 + a3.
    float re[16], im[16];

    // ---- layer 0: product-state fast path (RX,RY,RZ per wire on 2-vectors) ----
    {
        float pr[4][2], pim[4][2];
        #pragma unroll
        for (int w = 0; w < 4; ++w) {
            float cy, sy, cz, sz;
            __sincosf(0.5f * qp[w],     &sy, &cy);
            __sincosf(0.5f * qp[4 + w], &sz, &cz);
            // RX|0> = (cx, -i sx); RY: v0 = (cy*cx, sy*sx), v1 = (sy*cx, -cy*sx)
            const float v0r = cy * cx[w], v0i = sy * sx[w];
            const float v1r = sy * cx[w], v1i = -(cy * sx[w]);
            // RZ: w0 = v0*(cz - i sz), w1 = v1*(cz + i sz)
            pr[w][0]  = fmaf(v0r, cz,  v0i * sz);
            pim[w][0] = fmaf(v0i, cz, -v0r * sz);
            pr[w][1]  = fmaf(v1r, cz, -v1i * sz);
            pim[w][1] = fmaf(v1i, cz,  v1r * sz);
        }
        // tensor up: (w0 x w1), (w2 x w3), then full
        float t01r[4], t01i[4], t23r[4], t23i[4];
        #pragma unroll
        for (int a = 0; a < 2; ++a)
            #pragma unroll
            for (int c = 0; c < 2; ++c) {
                const int k = a * 2 + c;
                t01r[k] = fmaf(pr[0][a], pr[1][c], -pim[0][a] * pim[1][c]);
                t01i[k] = fmaf(pr[0][a], pim[1][c], pim[0][a] * pr[1][c]);
                t23r[k] = fmaf(pr[2][a], pr[3][c], -pim[2][a] * pim[3][c]);
                t23i[k] = fmaf(pr[2][a], pim[3][c], pim[2][a] * pr[3][c]);
            }
        #pragma unroll
        for (int i = 0; i < 16; ++i) {
            const int hi = i >> 2, lo = i & 3;
            re[i] = fmaf(t01r[hi], t23r[lo], -t01i[hi] * t23i[lo]);
            im[i] = fmaf(t01r[hi], t23i[lo],  t01i[hi] * t23r[lo]);
        }
    }
    CNOT_GATE(2, 3) CNOT_GATE(1, 2) CNOT_GATE(0, 1) CNOT_GATE(3, 0)

    // ---- layers 1,2: fused U = RZ*RY*RX per wire + CNOT ring ----
    #pragma unroll
    for (int l = 1; l <= 2; ++l) {
        const int o = 8 * l;
        #pragma unroll
        for (int w = 0; w < 4; ++w) {
            float cy, sy, cz, sz;
            __sincosf(0.5f * qp[o + w],     &sy, &cy);
            __sincosf(0.5f * qp[o + 4 + w], &sz, &cz);
            // alpha = (cy*cx, sy*sx), beta = (sy*cx, -cy*sx)
            const float ar = cy * cx[w], ai = sy * sx[w];
            const float br = sy * cx[w], bi = -(cy * sx[w]);
            // A = alpha*(cz - i sz), B = beta*(cz + i sz)
            const float Ar = fmaf(ar, cz,  ai * sz);
            const float Ai = fmaf(ai, cz, -ar * sz);
            const float Br = fmaf(br, cz, -bi * sz);
            const float Bi = fmaf(bi, cz,  br * sz);
            SU2_GATE(w, Ar, Ai, Br, Bi)
        }
        CNOT_GATE(2, 3) CNOT_GATE(1, 2) CNOT_GATE(0, 1) CNOT_GATE(3, 0)
    }

    // ---- layer 3: fused U = RY*RX (RZ dropped: phases don't change probs);
    //      final CNOT ring folded into measurement parity masks. ----
    #pragma unroll
    for (int w = 0; w < 4; ++w) {
        float cy, sy;
        __sincosf(0.5f * qp[24 + w], &sy, &cy);
        const float Ar = cy * cx[w], Ai = sy * sx[w];
        const float Br = sy * cx[w], Bi = -(cy * sx[w]);
        SU2_GATE(w, Ar, Ai, Br, Bi)
    }

    // probabilities
    float p[16];
    #pragma unroll
    for (int i = 0; i < 16; ++i) p[i] = fmaf(re[i], re[i], im[i] * im[i]);

    // Z-expectations with CNOT-ring permutation folded in:
    // b0=a0^a2^a3, b1=a0^a1, b2=a1^a2, b3=a2^a3  (a0=(i>>3)&1 ... a3=i&1)
    float ev[4];
    #pragma unroll
    for (int w = 0; w < 4; ++w) {
        float acc = 0.0f;
        #pragma unroll
        for (int i = 0; i < 16; ++i) {
            const int a0 = (i >> 3) & 1, a1 = (i >> 2) & 1, a2 = (i >> 1) & 1, a3 = i & 1;
            int s;
            if (w == 0)      s = a0 ^ a2 ^ a3;
            else if (w == 1) s = a0 ^ a1;
            else if (w == 2) s = a1 ^ a2;
            else             s = a2 ^ a3;
            acc += s ? -p[i] : p[i];
        }
        ev[w] = fmaxf(acc, 0.0f);   // relu
    }

    float4 o4;
    o4.x = fmaf(ev[0], Wmat[0],  fmaf(ev[1], Wmat[1],  fmaf(ev[2], Wmat[2],  fmaf(ev[3], Wmat[3],  bias[0]))));
    o4.y = fmaf(ev[0], Wmat[4],  fmaf(ev[1], Wmat[5],  fmaf(ev[2], Wmat[6],  fmaf(ev[3], Wmat[7],  bias[1]))));
    o4.z = fmaf(ev[0], Wmat[8],  fmaf(ev[1], Wmat[9],  fmaf(ev[2], Wmat[10], fmaf(ev[3], Wmat[11], bias[2]))));
    o4.w = fmaf(ev[0], Wmat[12], fmaf(ev[1], Wmat[13], fmaf(ev[2], Wmat[14], fmaf(ev[3], Wmat[15], bias[3]))));
    reinterpret_cast<float4*>(out)[b] = o4;
}

extern "C" void kernel_launch(void* const* d_in, const int* in_sizes, int n_in,
                              void* d_out, int out_size, void* d_ws, size_t ws_size,
                              hipStream_t stream) {
    const float* x     = (const float*)d_in[0];
    const float* w_emb = (const float*)d_in[1];
    const float* qp    = (const float*)d_in[2];
    const float* Wmat  = (const float*)d_in[3];
    const float* bias  = (const float*)d_in[4];
    float* out = (float*)d_out;

    const int nbatch = in_sizes[0] / 4;
    const int block = 256;
    const int grid = (nbatch + block - 1) / block;
    hipLaunchKernelGGL(qdqn_kernel, dim3(grid), dim3(block), 0, stream,
                       x, w_emb, qp, Wmat, bias, out, nbatch);
}